// Round 19
// baseline (152.592 us; speedup 1.0000x reference)
//
#include <hip/hip_runtime.h>
#include <math.h>

#define NB 64
#define TC 16
#define HC 32
#define NNODES 16384
#define NEDGES 131072
#define EPG 2048
#define EPSV 1e-15f

static inline int GRID(int n) { return (n + 255) / 256; }

template<int V> struct Log2 { static constexpr int v = 1 + Log2<V/2>::v; };
template<> struct Log2<1> { static constexpr int v = 0; };

__device__ inline float blk_sum256(float v, float* rbuf) {
    for (int o = 32; o > 0; o >>= 1) v += __shfl_xor(v, o);
    __syncthreads();
    if ((threadIdx.x & 63) == 0) rbuf[threadIdx.x >> 6] = v;
    __syncthreads();
    return rbuf[0] + rbuf[1] + rbuf[2] + rbuf[3];
}

__device__ inline float blk_sum512(float v, float* rbuf) {
    for (int o = 32; o > 0; o >>= 1) v += __shfl_xor(v, o);
    __syncthreads();
    if ((threadIdx.x & 63) == 0) rbuf[threadIdx.x >> 6] = v;
    __syncthreads();
    float s = 0.f;
#pragma unroll
    for (int i = 0; i < 8; ++i) s += rbuf[i];
    return s;
}

// ---------------- front: dense edge-built GEMM, 512 threads, b128 B-reads ----------------
__global__ __launch_bounds__(512) void k_front(
        const int* __restrict__ esrc, const int* __restrict__ edst,
        const float* __restrict__ ea, const float* __restrict__ pos,
        const float* __restrict__ W1, const float* __restrict__ b1,
        const float* __restrict__ Wp1, const float* __restrict__ bp1,
        float* __restrict__ z, float* __restrict__ dinv_g,
        float* __restrict__ p1, float* __restrict__ mc) {
    __shared__ float dinvs[256];
    __shared__ __align__(16) float as_[1152];   // 32x36
    __shared__ __align__(16) float bs[1536];    // 32x48
    __shared__ __align__(16) float zs[1536];    // 32x48
    __shared__ float xm[1024];                  // 32x32
    __shared__ float s1[2048];                  // 32x64
    __shared__ __align__(16) float wp[2048];    // 32x64
    __shared__ float W1s[96];
    __shared__ float b1s[32];
    __shared__ float bp1s[64];

    int bid = blockIdx.x;
    int b = (bid & 7) * 8 + (bid >> 6);
    int dtile = ((bid >> 3) & 7) * 32;
    int tid = threadIdx.x;
    if (bid == 0 && tid < 2) mc[tid] = 0.f;
    ((float4*)wp)[tid] = ((const float4*)Wp1)[tid];     // 512 float4
    if (tid < 96) W1s[tid] = W1[tid];
    if (tid < 32) b1s[tid] = b1[tid];
    if (tid < 64) bp1s[tid] = bp1[tid];

    int ebase = b * EPG;
    int svr[4], dvr[4];
    float evr[4];
#pragma unroll
    for (int j = 0; j < 4; ++j) {
        int e = ebase + tid + j * 512;
        svr[j] = esrc[e] & 255;
        dvr[j] = edst[e] & 255;
        evr[j] = ea[e];
    }
    if (tid < 256) dinvs[tid] = 1.0f;
    __syncthreads();
#pragma unroll
    for (int j = 0; j < 4; ++j) atomicAdd(&dinvs[dvr[j]], evr[j]);
    __syncthreads();
    float dvv = 0.f;
    if (tid < 256) {
        float dg = dinvs[tid];
        dvv = (dg > 0.f) ? rsqrtf(dg) : 0.f;
    }
    __syncthreads();
    if (tid < 256) dinvs[tid] = dvv;
    __syncthreads();
    if (dtile == 0 && tid < 256) dinv_g[b * 256 + tid] = dinvs[tid];

    int d = tid >> 4, q = tid & 15;
    bool act = (q < 12);
    float4 acc = make_float4(0.f, 0.f, 0.f, 0.f);
    const float* pbase = pos + (size_t)b * 256 * 48;
    for (int s0 = 0; s0 < 256; s0 += 32) {
        for (int i = tid; i < 288; i += 512)
            ((float4*)as_)[i] = make_float4(0.f, 0.f, 0.f, 0.f);
        __syncthreads();
#pragma unroll
        for (int j = 0; j < 4; ++j) {
            int dr = dvr[j] - dtile, sc = svr[j] - s0;
            if ((unsigned)dr < 32u && (unsigned)sc < 32u)
                atomicAdd(&as_[dr * 36 + sc], evr[j]);
        }
        for (int i = tid; i < 384; i += 512) {
            int r = i / 12, c = i % 12;
            float4 v = *(const float4*)(pbase + (size_t)(s0 + r) * 48 + c * 4);
            float dd = dinvs[s0 + r];
            v.x *= dd; v.y *= dd; v.z *= dd; v.w *= dd;
            *(float4*)(bs + r * 48 + c * 4) = v;
        }
        __syncthreads();
        if (act) {
#pragma unroll 8
            for (int sp = 0; sp < 32; ++sp) {
                float a = as_[d * 36 + sp];
                float4 bv = *(const float4*)&bs[sp * 48 + q * 4];
                acc.x += a * bv.x;
                acc.y += a * bv.y;
                acc.z += a * bv.z;
                acc.w += a * bv.w;
            }
        }
        __syncthreads();
    }
    if (act) {
        float dd = dinvs[dtile + d];
        float d2 = dd * dd;
        size_t goff = ((size_t)(b * 256 + dtile + d)) * 48 + q * 4;
        float4 pv = *(const float4*)(pos + goff);
        float4 zv;
        zv.x = acc.x * dd; zv.y = acc.y * dd; zv.z = acc.z * dd; zv.w = acc.w * dd;
        *(float4*)(z + goff) = zv;
        float4 av;
        av.x = zv.x + pv.x * d2;
        av.y = zv.y + pv.y * d2;
        av.z = zv.z + pv.z * d2;
        av.w = zv.w + pv.w * d2;
        *(float4*)&zs[d * 48 + q * 4] = av;
    }
    __syncthreads();
    {
        int h = tid & 31, ng = tid >> 5;
        float w0 = W1s[h], w1 = W1s[32 + h], w2 = W1s[64 + h], bb = b1s[h];
#pragma unroll
        for (int j = 0; j < 2; ++j) {
            int nn = ng * 2 + j;
            float a = 0.f;
#pragma unroll
            for (int t = 0; t < 16; ++t) {
                const float* ap = &zs[nn * 48 + t * 3];
                float y = fmaxf(ap[0] * w0 + ap[1] * w1 + ap[2] * w2 + bb, 0.f);
                a += y;
            }
            xm[nn * 32 + h] = a * (1.0f / 16.0f);
        }
    }
    __syncthreads();
    for (int i = tid; i < 2048; i += 512) {
        int n = i >> 6, k = i & 63;
        float a = bp1s[k];
#pragma unroll 8
        for (int h2 = 0; h2 < 32; ++h2) a += xm[n * 32 + h2] * wp[h2 * 64 + k];
        s1[i] = tanhf(a);
    }
    __syncthreads();
    {
        int wid = tid >> 6, lane = tid & 63;
        for (int r0 = wid; r0 < 32; r0 += 8) {
            float v = s1[r0 * 64 + lane];
            float m = v;
            for (int o = 32; o > 0; o >>= 1) m = fmaxf(m, __shfl_xor(m, o));
            float e = expf(v - m);
            float s = e;
            for (int o = 32; o > 0; o >>= 1) s += __shfl_xor(s, o);
            p1[((size_t)b * 256 + dtile + r0) * 64 + lane] = e / s;
        }
    }
}

// ---------------- pool1 fused: recompute y from z, pool in LDS ----------------
__global__ __launch_bounds__(256) void k_pool1f(
        const float* __restrict__ z, const float* __restrict__ pos,
        const float* __restrict__ dinv, const float* __restrict__ p1,
        const float* __restrict__ W1, const float* __restrict__ b1,
        float* __restrict__ X1A) {
    __shared__ __align__(16) float ps[4096];
    __shared__ __align__(16) float ys[4096];
    __shared__ float zc[384];
    __shared__ float pc[384];
    __shared__ float dv[64];
    __shared__ float W1s[96];
    __shared__ float b1s[32];
    int bid = blockIdx.x;
    int b = (bid & 7) * 8 + (bid >> 6);
    int t0 = ((bid >> 3) & 7) * 2;
    int tid = threadIdx.x;
    if (tid < 96) W1s[tid] = W1[tid];
    if (tid < 32) b1s[tid] = b1[tid];
    __syncthreads();
    int hh = tid & 31;
    float w0 = W1s[hh], w1 = W1s[32 + hh], w2 = W1s[64 + hh], bb = b1s[hh];
    int th = tid >> 7, r = tid & 127;
    int k0 = (r >> 3) * 4, h0 = (r & 7) * 4;
    float acc[4][4];
#pragma unroll
    for (int a = 0; a < 4; ++a)
#pragma unroll
        for (int c = 0; c < 4; ++c) acc[a][c] = 0.f;
    for (int n0 = 0; n0 < 256; n0 += 64) {
        for (int i = tid; i < 1024; i += 256)
            ((float4*)ps)[i] = ((const float4*)(p1 + ((size_t)b * 256 + n0) * 64))[i];
        if (tid < 192) {
            int n = tid / 3, c = tid % 3;
            size_t off = ((size_t)(b * 256 + n0 + n)) * 48 + t0 * 3 + c * 2;
            *(float2*)&zc[n * 6 + c * 2] = *(const float2*)(z + off);
            *(float2*)&pc[n * 6 + c * 2] = *(const float2*)(pos + off);
        }
        if (tid < 64) dv[tid] = dinv[b * 256 + n0 + tid];
        __syncthreads();
        int g = tid >> 5;
#pragma unroll
        for (int j = 0; j < 16; ++j) {
            int pidx = g * 16 + j;
            int t = pidx >> 6, nn = pidx & 63;
            float d2 = dv[nn] * dv[nn];
            const float* zp = &zc[nn * 6 + t * 3];
            const float* pp = &pc[nn * 6 + t * 3];
            float a0 = zp[0] + pp[0] * d2;
            float a1 = zp[1] + pp[1] * d2;
            float a2 = zp[2] + pp[2] * d2;
            ys[t * 2048 + nn * 32 + hh] = fmaxf(a0 * w0 + a1 * w1 + a2 * w2 + bb, 0.f);
        }
        __syncthreads();
#pragma unroll 4
        for (int n = 0; n < 64; ++n) {
            float4 kv4 = *(const float4*)&ps[n * 64 + k0];
            float4 xv4 = *(const float4*)&ys[th * 2048 + n * 32 + h0];
            float kv[4] = {kv4.x, kv4.y, kv4.z, kv4.w};
            float xv[4] = {xv4.x, xv4.y, xv4.z, xv4.w};
#pragma unroll
            for (int a = 0; a < 4; ++a)
#pragma unroll
                for (int c = 0; c < 4; ++c) acc[a][c] += kv[a] * xv[c];
        }
        __syncthreads();
    }
    float* ob = X1A + (((size_t)(b * 16 + t0 + th) * 64 + k0) * 32 + h0);
#pragma unroll
    for (int a = 0; a < 4; ++a) {
        float4 v = {acc[a][0], acc[a][1], acc[a][2], acc[a][3]};
        *(float4*)(ob + (size_t)a * 32) = v;
    }
}

// ---------------- fused L1 adjacency-apply + partial GEMM (was adjp2 + ssgp) ----------------
// grid NB*4; b = (bid&7)*8 + idx/4, split = idx%4, idx = bid>>3. 64-row n-chunk.
__global__ __launch_bounds__(256) void k_adjssg(
        const int* __restrict__ esrc, const int* __restrict__ edst,
        const float* __restrict__ p, float* __restrict__ G,
        float* __restrict__ Gden) {
    __shared__ __align__(16) float cnt[32 * 260];   // 33280 B
    __shared__ __align__(16) float ps[64 * 64];     // 16384 B
    __shared__ __align__(16) float tmpL[64 * 64];   // 16384 B
    __shared__ float dfl[64];
    __shared__ float rbuf[4];
    int bid = blockIdx.x;
    int idx = bid >> 3;
    int b = (bid & 7) * 8 + idx / 4;
    int split = idx % 4;
    int n0 = split * 64;
    int tid = threadIdx.x;
    int ebase = b * EPG;

    // Phase A (x2): build counts for 32 rows, accumulate tmp into LDS
    for (int half = 0; half < 2; ++half) {
        int nh0 = n0 + half * 32;
        for (int i = tid; i < 2080; i += 256)
            ((float4*)cnt)[i] = make_float4(0.f, 0.f, 0.f, 0.f);
        __syncthreads();
#pragma unroll
        for (int j = 0; j < 8; ++j) {
            int e = ebase + tid + j * 256;
            int sv = esrc[e] & 255;
            int nr = sv - nh0;
            if ((unsigned)nr < 32u)
                atomicAdd(&cnt[nr * 260 + (edst[e] & 255)], 1.0f);
        }
        __syncthreads();
        int n = tid >> 3, l0 = (tid & 7) * 8;
        float acc[8];
#pragma unroll
        for (int j = 0; j < 8; ++j) acc[j] = 0.f;
        float rs = 0.f;
        for (int m0 = 0; m0 < 256; m0 += 64) {
            for (int i = tid; i < 1024; i += 256)
                ((float4*)ps)[i] = ((const float4*)(p + ((size_t)b * 256 + m0) * 64))[i];
            __syncthreads();
#pragma unroll 4
            for (int m = 0; m < 64; ++m) {
                float av = cnt[n * 260 + m0 + m];
                rs += av;
                float4 p0 = *(const float4*)&ps[m * 64 + l0];
                float4 p1v = *(const float4*)&ps[m * 64 + l0 + 4];
                acc[0] += av * p0.x; acc[1] += av * p0.y; acc[2] += av * p0.z; acc[3] += av * p0.w;
                acc[4] += av * p1v.x; acc[5] += av * p1v.y; acc[6] += av * p1v.z; acc[7] += av * p1v.w;
            }
            __syncthreads();
        }
#pragma unroll
        for (int j = 0; j < 8; ++j)
            tmpL[(half * 32 + n) * 64 + l0 + j] = acc[j];
        if ((tid & 7) == 0) dfl[half * 32 + n] = rs;
        __syncthreads();
    }

    // Phase B: stage this chunk's p rows; den; 4x8 register-tile GEMM over [p | tmpL]
    for (int i = tid; i < 1024; i += 256)
        ((float4*)ps)[i] = ((const float4*)(p + ((size_t)b * 256 + n0) * 64))[i];
    __syncthreads();
    float den = 0.f;
    for (int i = tid; i < 1024; i += 256) {
        float4 v = ((const float4*)ps)[i];
        den += (v.x * v.x + v.y * v.y + v.z * v.z + v.w * v.w) * dfl[i >> 4];
    }
    int kt = tid >> 4, lt = tid & 15;
    int k0 = kt * 4, l0g = lt * 8;
    const float* lsrc = (lt < 8) ? (ps + l0g) : (tmpL + (l0g - 64));
    float accG[4][8];
#pragma unroll
    for (int r = 0; r < 4; ++r)
#pragma unroll
        for (int c = 0; c < 8; ++c) accG[r][c] = 0.f;
#pragma unroll 4
    for (int nn = 0; nn < 64; ++nn) {
        float kv[4], lv[8];
#pragma unroll
        for (int r = 0; r < 4; ++r) kv[r] = ps[nn * 64 + k0 + r];
#pragma unroll
        for (int c = 0; c < 8; ++c) lv[c] = lsrc[nn * 64 + c];
#pragma unroll
        for (int r = 0; r < 4; ++r)
#pragma unroll
            for (int c = 0; c < 8; ++c) accG[r][c] += kv[r] * lv[c];
    }
    float* Gb = G + ((size_t)split * NB + b) * 8192;
#pragma unroll
    for (int r = 0; r < 4; ++r)
#pragma unroll
        for (int c = 0; c < 8; ++c)
            Gb[(k0 + r) * 128 + l0g + c] = accG[r][c];
    float dt = blk_sum256(den, rbuf);
    if (tid == 0) Gden[(size_t)split * NB + b] = dt;
}

// ---------------- tail A: finish L1 + per-batch planning, 512 threads ----------------
__global__ __launch_bounds__(512) void k_tail_a(
        const float* __restrict__ X1A, const float* __restrict__ GBUF1,
        const float* __restrict__ GDEN1, const float* __restrict__ p1,
        const float* __restrict__ Wrel2, const float* __restrict__ brel2,
        const float* __restrict__ Wroot2,
        const float* __restrict__ Wp2, const float* __restrict__ bp2,
        const float* __restrict__ Wrel3, const float* __restrict__ brel3,
        const float* __restrict__ Wroot3,
        const float* __restrict__ Wp3, const float* __restrict__ bp3,
        float* __restrict__ OADJ1G, float* __restrict__ P2G,
        float* __restrict__ OADJ2G, float* __restrict__ P3G,
        float* __restrict__ OADJ3G, float* __restrict__ outagg,
        float* __restrict__ mc_out, float* __restrict__ or_out) {
    __shared__ __align__(16) float lds[16160];
    float* P2     = lds;            // 64x36
    float* XM2    = lds + 2304;     // 64x36
    float* OADJ2L = lds + 4608;     // 32x36
    float* P3L    = lds + 5760;     // 32x8
    float* OADJ3L = lds + 6016;     // 8x8
    float* DF3    = lds + 6080;     // 32
    float* DVV    = lds + 6112;     // 40
    float* RBUF   = lds + 6152;     // 8
    float* OADJ1s = lds + 6160;     // 64x68
    float* S      = lds + 10512;    // scratch (max use 5504)
    float* DF2    = lds + 16080;    // 64 (persist)

    int bid = blockIdx.x;
    int b = ((bid & 7) << 3) | (bid >> 3);
    int tid = threadIdx.x;

    // ---- Phase F: finish L1
    {
        float* FS = lds;           // 64x65
        float* FO = lds + 4160;
        float* FD = lds + 8320;
        float* FR = lds + 8384;
#pragma unroll
        for (int j = 0; j < 8; ++j) {
            int i = tid + j * 512;
            int k = i >> 6, l = i & 63;
            float sv = 0.f, ov = 0.f;
#pragma unroll
            for (int s = 0; s < 4; ++s) {
                const float* Gb = GBUF1 + ((size_t)s * NB + b) * 8192;
                sv += Gb[k * 128 + l];
                ov += Gb[k * 128 + 64 + l];
            }
            FS[k * 65 + l] = sv;
            FO[k * 65 + l] = ov;
        }
        __syncthreads();
        float ssn2 = 0.f;
#pragma unroll
        for (int j = 0; j < 8; ++j) {
            int i = tid + j * 512;
            float v = FS[(i >> 6) * 65 + (i & 63)];
            ssn2 += v * v;
        }
        float num = 0.f;
        if (tid < 64) num = FO[tid * 65 + tid];
        float den_t = 0.f;
#pragma unroll
        for (int s = 0; s < 4; ++s) den_t += GDEN1[(size_t)s * NB + b];
        float ssn2_t = blk_sum512(ssn2, FR);
        float num_t = blk_sum512(num, FR);
        float inv = 1.0f / sqrtf(ssn2_t);
        float dk = rsqrtf(64.0f);
        float o2 = 0.f;
#pragma unroll
        for (int j = 0; j < 8; ++j) {
            int i = tid + j * 512;
            int k = i >> 6, l = i & 63;
            float v = FS[k * 65 + l] * inv - ((k == l) ? dk : 0.f);
            o2 += v * v;
        }
        float o2_t = blk_sum512(o2, FR);
        if (tid == 0) {
            atomicAdd(mc_out, -(num_t / den_t) * (1.0f / NB));
            atomicAdd(or_out, sqrtf(o2_t) * (1.0f / NB));
        }
        if (tid < 64) {
            float rs = 0.f;
            for (int l = 0; l < 64; ++l) rs += FO[tid * 65 + l];
            rs -= FO[tid * 65 + tid];
            FD[tid] = sqrtf(rs) + EPSV;
        }
        __syncthreads();
        float ov8[8];
#pragma unroll
        for (int j = 0; j < 8; ++j) {
            int i = tid + j * 512;
            int k = i >> 6, l = i & 63;
            ov8[j] = (k == l) ? 0.f : FO[k * 65 + l] / (FD[k] * FD[l]);
        }
        __syncthreads();
#pragma unroll
        for (int j = 0; j < 8; ++j) {
            int i = tid + j * 512;
            int k = i >> 6, l = i & 63;
            OADJ1s[k * 68 + l] = ov8[j];
            OADJ1G[(size_t)b * 4096 + i] = ov8[j];
        }
        __syncthreads();
        if (tid < 64) {
            float rs = 0.f;
            for (int l = 0; l < 64; ++l) rs += OADJ1s[tid * 68 + l];
            DF2[tid] = rs;
        }
        __syncthreads();
    }

    // ---- Phase 0: XM1A = mean_t X1A; XM2 = graphconv2(XM1A)
    float* XM1A = S;
    for (int i = tid; i < 2048; i += 512) {
        float s = 0.f;
        for (int t = 0; t < 16; ++t) s += X1A[((size_t)b * 16 + t) * 2048 + i];
        XM1A[(i >> 5) * 36 + (i & 31)] = s * (1.0f / 16.0f);
    }
    {
        float* WR = P2;
        float* WO = P2 + 1024;
        for (int i = tid; i < 1024; i += 512) { WR[i] = Wrel2[i]; WO[i] = Wroot2[i]; }
        __syncthreads();
        float* C1 = S + 2304;
        int n = tid >> 3, j0 = (tid & 7) * 4;
        float a4[4] = {0, 0, 0, 0};
        for (int m = 0; m < 64; ++m) {
            float av = OADJ1s[n * 68 + m];
            float4 xv = *(const float4*)&XM1A[m * 36 + j0];
            a4[0] += av * xv.x; a4[1] += av * xv.y; a4[2] += av * xv.z; a4[3] += av * xv.w;
        }
        __syncthreads();
#pragma unroll
        for (int j = 0; j < 4; ++j) C1[n * 36 + j0 + j] = a4[j];
        __syncthreads();
        float o4[4];
#pragma unroll
        for (int j = 0; j < 4; ++j) o4[j] = brel2[j0 + j];
        for (int h = 0; h < 32; ++h) {
            float c1v = C1[n * 36 + h];
            float xav = XM1A[n * 36 + h];
            float4 wr = *(const float4*)&WR[h * 32 + j0];
            float4 wo = *(const float4*)&WO[h * 32 + j0];
            o4[0] += c1v * wr.x + xav * wo.x;
            o4[1] += c1v * wr.y + xav * wo.y;
            o4[2] += c1v * wr.z + xav * wo.z;
            o4[3] += c1v * wr.w + xav * wo.w;
        }
        __syncthreads();
#pragma unroll
        for (int j = 0; j < 4; ++j) XM2[n * 36 + j0 + j] = o4[j];
        __syncthreads();
    }
    // ---- Phase 2: P2 = softmax(tanh(XM2@Wp2+bp2))
    {
        float* S2 = S;
        float* WP2s = S + 2048;
        for (int i = tid; i < 1024; i += 512) WP2s[i] = Wp2[i];
        __syncthreads();
        for (int i = tid; i < 2048; i += 512) {
            int n = i >> 5, k = i & 31;
            float a = bp2[k];
            for (int h = 0; h < 32; ++h) a += XM2[n * 36 + h] * WP2s[h * 32 + k];
            S2[i] = tanhf(a);
        }
        __syncthreads();
        int lane = tid & 31, rr = tid >> 5;
        for (int r0 = 0; r0 < 64; r0 += 16) {
            int row = r0 + rr;
            float v = S2[row * 32 + lane];
            float m = v;
            for (int o = 16; o > 0; o >>= 1) m = fmaxf(m, __shfl_xor(m, o, 32));
            float e = expf(v - m);
            float s = e;
            for (int o = 16; o > 0; o >>= 1) s += __shfl_xor(s, o, 32);
            P2[row * 36 + lane] = e / s;
        }
        __syncthreads();
        for (int i = tid; i < 2048; i += 512)
            P2G[(size_t)b * 2048 + i] = P2[(i >> 5) * 36 + (i & 31)];
    }
    // ---- Phase 3: TMP2 = OADJ1 @ P2
    float* TMP2 = S;
    {
        int n = tid >> 3, l0 = (tid & 7) * 4;
        float a4[4] = {0, 0, 0, 0};
        for (int m = 0; m < 64; ++m) {
            float av = OADJ1s[n * 68 + m];
            float4 pv = *(const float4*)&P2[m * 36 + l0];
            a4[0] += av * pv.x; a4[1] += av * pv.y; a4[2] += av * pv.z; a4[3] += av * pv.w;
        }
        __syncthreads();
#pragma unroll
        for (int j = 0; j < 4; ++j) TMP2[n * 36 + l0 + j] = a4[j];
        __syncthreads();
    }
    // ---- Phase 4: GS/GO, losses L2, OADJ2L, DF3
    {
        float* GS = S + 2304;
        float* GO = S + 3360;
        int k = tid >> 4, l0 = (tid & 15) * 2;
        float as2[2] = {0, 0}, ao2[2] = {0, 0};
        for (int n = 0; n < 64; ++n) {
            float pv = P2[n * 36 + k];
            float2 lp = *(const float2*)&P2[n * 36 + l0];
            float2 lt = *(const float2*)&TMP2[n * 36 + l0];
            as2[0] += pv * lp.x; as2[1] += pv * lp.y;
            ao2[0] += pv * lt.x; ao2[1] += pv * lt.y;
        }
        GS[k * 33 + l0] = as2[0]; GS[k * 33 + l0 + 1] = as2[1];
        GO[k * 33 + l0] = ao2[0]; GO[k * 33 + l0 + 1] = ao2[1];
        __syncthreads();
        float den = 0.f;
        for (int i = tid; i < 2048; i += 512) {
            float pv = P2[(i >> 5) * 36 + (i & 31)];
            den += pv * pv * DF2[i >> 5];
        }
        float ssn2 = 0.f;
        for (int i = tid; i < 1024; i += 512) {
            float v = GS[(i >> 5) * 33 + (i & 31)];
            ssn2 += v * v;
        }
        float num = 0.f;
        if (tid < 32) num = GO[tid * 33 + tid];
        float den_t = blk_sum512(den, RBUF);
        float ssn2_t = blk_sum512(ssn2, RBUF);
        float num_t = blk_sum512(num, RBUF);
        float inv = 1.0f / sqrtf(ssn2_t);
        float dk = rsqrtf(32.0f);
        float o2 = 0.f;
        for (int i = tid; i < 1024; i += 512) {
            int kk = i >> 5, ll = i & 31;
            float v = GS[kk * 33 + ll] * inv - ((kk == ll) ? dk : 0.f);
            o2 += v * v;
        }
        float o2_t = blk_sum512(o2, RBUF);
        if (tid == 0) {
            atomicAdd(mc_out, -(num_t / den_t) * (1.0f / NB));
            atomicAdd(or_out, sqrtf(o2_t) * (1.0f / NB));
        }
        if (tid < 32) {
            float rs = 0.f;
            for (int l = 0; l < 32; ++l) rs += GO[tid * 33 + l];
            rs -= GO[tid * 33 + tid];
            DVV[tid] = sqrtf(rs) + EPSV;
        }
        __syncthreads();
        for (int i = tid; i < 1024; i += 512) {
            int kk = i >> 5, ll = i & 31;
            float v = (kk == ll) ? 0.f : GO[kk * 33 + ll] / (DVV[kk] * DVV[ll]);
            OADJ2L[kk * 36 + ll] = v;
            OADJ2G[(size_t)b * 1024 + i] = v;
        }
        __syncthreads();
        if (tid < 32) {
            float s = 0.f;
            for (int l = 0; l < 32; ++l) s += OADJ2L[tid * 36 + l];
            DF3[tid] = s;
        }
        __syncthreads();
    }
    // ---- Phase 5: XM2A = P2^T @ XM2
    float* XM2A = S;
    {
        int k = tid >> 4, h0 = (tid & 15) * 2;
        float a2[2] = {0, 0};
        for (int n = 0; n < 64; ++n) {
            float pv = P2[n * 36 + k];
            float2 xv = *(const float2*)&XM2[n * 36 + h0];
            a2[0] += pv * xv.x; a2[1] += pv * xv.y;
        }
        __syncthreads();
        XM2A[k * 36 + h0] = a2[0];
        XM2A[k * 36 + h0 + 1] = a2[1];
        __syncthreads();
    }
    // ---- Phase 6: XM2B = graphconv3(XM2A)
    float* XM2B = S + 4352;
    {
        float* WREL3s = S + 1152;
        float* WROOT3s = S + 2176;
        float* C1 = S + 3200;
        for (int i = tid; i < 1024; i += 512) {
            WREL3s[i] = Wrel3[i];
            WROOT3s[i] = Wroot3[i];
        }
        __syncthreads();
        int n = tid >> 4, j0 = (tid & 15) * 2;
        float a2[2] = {0, 0};
        for (int m = 0; m < 32; ++m) {
            float av = OADJ2L[n * 36 + m];
            float2 xv = *(const float2*)&XM2A[m * 36 + j0];
            a2[0] += av * xv.x; a2[1] += av * xv.y;
        }
        __syncthreads();
        C1[n * 36 + j0] = a2[0];
        C1[n * 36 + j0 + 1] = a2[1];
        __syncthreads();
        float o2v[2];
        o2v[0] = brel3[j0]; o2v[1] = brel3[j0 + 1];
        for (int h = 0; h < 32; ++h) {
            float c1v = C1[n * 36 + h];
            float xav = XM2A[n * 36 + h];
            float2 wr = *(const float2*)&WREL3s[h * 32 + j0];
            float2 wo = *(const float2*)&WROOT3s[h * 32 + j0];
            o2v[0] += c1v * wr.x + xav * wo.x;
            o2v[1] += c1v * wr.y + xav * wo.y;
        }
        __syncthreads();
        XM2B[n * 36 + j0] = o2v[0];
        XM2B[n * 36 + j0 + 1] = o2v[1];
        __syncthreads();
    }
    // ---- Phase 7: P3 = softmax(tanh(XM2B@Wp3+bp3))
    {
        float* WP3s = S;
        for (int i = tid; i < 256; i += 512) WP3s[i] = Wp3[i];
        __syncthreads();
        if (tid < 256) {
            int n = tid >> 3, kk = tid & 7;
            float a = bp3[kk];
            for (int h = 0; h < 32; ++h) a += XM2B[n * 36 + h] * WP3s[h * 8 + kk];
            float v = tanhf(a);
            float m = v;
            for (int o = 4; o > 0; o >>= 1) m = fmaxf(m, __shfl_xor(m, o, 8));
            float e = expf(v - m);
            float s = e;
            for (int o = 4; o > 0; o >>= 1) s += __shfl_xor(s, o, 8);
            P3L[n * 8 + kk] = e / s;
        }
        __syncthreads();
        if (tid < 256) P3G[(size_t)b * 256 + tid] = P3L[tid];
        __syncthreads();
    }
    // ---- Phase 8: L3 losses + OADJ3
    {
        float* TMP3 = S;
        float* GS3 = S + 256;
        float* GO3 = S + 336;
        if (tid < 256) {
            int n = tid >> 3, l = tid & 7;
            float a = 0.f;
            for (int m = 0; m < 32; ++m) a += OADJ2L[n * 36 + m] * P3L[m * 8 + l];
            TMP3[n * 8 + l] = a;
        }
        __syncthreads();
        if (tid < 64) {
            int k = tid >> 3, ll = tid & 7;
            float accs = 0.f, acco = 0.f;
            for (int nn = 0; nn < 32; ++nn) {
                float pv = P3L[nn * 8 + k];
                accs += pv * P3L[nn * 8 + ll];
                acco += pv * TMP3[nn * 8 + ll];
            }
            GS3[k * 9 + ll] = accs;
            GO3[k * 9 + ll] = acco;
        }
        __syncthreads();
        float den = 0.f;
        if (tid < 256) {
            float pv = P3L[tid];
            den = pv * pv * DF3[tid >> 3];
        }
        float ssn2 = 0.f;
        if (tid < 64) {
            float v = GS3[(tid >> 3) * 9 + (tid & 7)];
            ssn2 = v * v;
        }
        float num = 0.f;
        if (tid < 8) num = GO3[tid * 9 + tid];
        float den_t = blk_sum512(den, RBUF);
        float ssn2_t = blk_sum512(ssn2, RBUF);
        float num_t = blk_sum512(num, RBUF);
        float inv = 1.0f / sqrtf(ssn2_t);
        float dk = rsqrtf(8.0f);
        float o2 = 0.f;
        if (tid < 64) {
            int k = tid >> 3, ll = tid & 7;
            float v = GS3[k * 9 + ll] * inv - ((k == ll) ? dk : 0.f);
            o2 = v * v;
        }
        float o2_t = blk_sum512(o2, RBUF);
        if (tid == 0) {
            atomicAdd(mc_out, -(num_t / den_t) * (1.0f / NB));
            atomicAdd(or_out, sqrtf(o2_t) * (1.0f / NB));
        }
        if (tid < 8) {
            float rs = 0.f;
            for (int ll = 0; ll < 8; ++ll) rs += GO3[tid * 9 + ll];
            rs -= GO3[tid * 9 + tid];
            DVV[32 + tid] = sqrtf(rs) + EPSV;
        }
        __syncthreads();
        if (tid < 64) {
            int k = tid >> 3, ll = tid & 7;
            float v = (k == ll) ? 0.f : GO3[k * 9 + ll] / (DVV[32 + k] * DVV[32 + ll]);
            OADJ3L[tid] = v;
            OADJ3G[(size_t)b * 64 + tid] = v;
        }
        __syncthreads();
    }
    // ---- Phase 9: agg = p1 @ (P2 @ P3)
    {
        float* Q = S;
        {
            int k = tid >> 3, m = tid & 7;
            float a = 0.f;
            for (int l = 0; l < 32; ++l) a += P2[k * 36 + l] * P3L[l * 8 + m];
            Q[tid] = a;
        }
        __syncthreads();
        int row = tid >> 1, m0 = (tid & 1) * 4;
        const float* p1r = p1 + ((size_t)b * 256 + row) * 64;
        float a4[4] = {0, 0, 0, 0};
        for (int k = 0; k < 64; ++k) {
            float pv = p1r[k];
#pragma unroll
            for (int m = 0; m < 4; ++m) a4[m] += pv * Q[k * 8 + m0 + m];
        }
#pragma unroll
        for (int m = 0; m < 4; ++m)
            outagg[((size_t)b * 256 + row) * 8 + m0 + m] = a4[m];
    }
}

// ---------------- tail B: per-(b,t) heavy path, gc2 fused, fully LDS-resident ----------------
__global__ __launch_bounds__(256) void k_tail_b(
        const float* __restrict__ X1A, const float* __restrict__ oadj1,
        const float* __restrict__ P2G, const float* __restrict__ OADJ2G,
        const float* __restrict__ P3G, const float* __restrict__ OADJ3G,
        const float* __restrict__ Wrel2, const float* __restrict__ brel2,
        const float* __restrict__ Wroot2,
        const float* __restrict__ Wrel3, const float* __restrict__ brel3,
        const float* __restrict__ Wroot3,
        const float* __restrict__ Wrel4, const float* __restrict__ brel4,
        const float* __restrict__ Wroot4,
        float* __restrict__ outx) {
    __shared__ float A[13408];
    float* X1AT = A;               // 64x36
    float* OADJ1s = A + 2304;      // 64x68
    float* WrelS = A + 6656;       // 1024
    float* WrootS = A + 7680;      // 1024
    float* C1a = A + 8704;         // 64x36
    float* X1B = A + 11008;        // 64x36
    int bid = blockIdx.x;
    int idxg = bid >> 3;
    int t = idxg & 15;
    int b = (bid & 7) * 8 + (idxg >> 4);
    int bt = b * 16 + t;
    int tid = threadIdx.x;
    for (int i = tid; i < 2048; i += 256)
        X1AT[(i >> 5) * 36 + (i & 31)] = X1A[(size_t)bt * 2048 + i];
    for (int i = tid; i < 4096; i += 256)
        OADJ1s[(i >> 6) * 68 + (i & 63)] = oadj1[(size_t)b * 4096 + i];
    for (int i = tid; i < 1024; i += 256) {
        WrelS[i] = Wrel2[i];
        WrootS[i] = Wroot2[i];
    }
    __syncthreads();
    {
        int n = tid >> 2, j0 = (tid & 3) * 8;
        float a8[8];
#pragma unroll
        for (int j = 0; j < 8; ++j) a8[j] = 0.f;
        for (int m = 0; m < 64; ++m) {
            float av = OADJ1s[n * 68 + m];
            float4 x1 = *(const float4*)&X1AT[m * 36 + j0];
            float4 x2 = *(const float4*)&X1AT[m * 36 + j0 + 4];
            a8[0] += av * x1.x; a8[1] += av * x1.y; a8[2] += av * x1.z; a8[3] += av * x1.w;
            a8[4] += av * x2.x; a8[5] += av * x2.y; a8[6] += av * x2.z; a8[7] += av * x2.w;
        }
        __syncthreads();
#pragma unroll
        for (int j = 0; j < 8; ++j) C1a[n * 36 + j0 + j] = a8[j];
        __syncthreads();
        float o8[8];
#pragma unroll
        for (int j = 0; j < 8; ++j) o8[j] = brel2[j0 + j];
        for (int h = 0; h < 32; ++h) {
            float c1v = C1a[n * 36 + h];
            float xav = X1AT[n * 36 + h];
            float4 wr1 = *(const float4*)&WrelS[h * 32 + j0];
            float4 wr2 = *(const float4*)&WrelS[h * 32 + j0 + 4];
            float4 wo1 = *(const float4*)&WrootS[h * 32 + j0];
            float4 wo2 = *(const float4*)&WrootS[h * 32 + j0 + 4];
            o8[0] += c1v * wr1.x + xav * wo1.x; o8[1] += c1v * wr1.y + xav * wo1.y;
            o8[2] += c1v * wr1.z + xav * wo1.z; o8[3] += c1v * wr1.w + xav * wo1.w;
            o8[4] += c1v * wr2.x + xav * wo2.x; o8[5] += c1v * wr2.y + xav * wo2.y;
            o8[6] += c1v * wr2.z + xav * wo2.z; o8[7] += c1v * wr2.w + xav * wo2.w;
        }
        __syncthreads();
#pragma unroll
        for (int j = 0; j < 8; ++j) X1B[n * 36 + j0 + j] = o8[j];
        __syncthreads();
    }
    float* P2s = A;                // 64x36
    float* X2A = A + 2304;         // 32x36
    for (int i = tid; i < 2048; i += 256)
        P2s[(i >> 5) * 36 + (i & 31)] = P2G[(size_t)b * 2048 + i];
    __syncthreads();
    {
        int k = tid >> 3, h0 = (tid & 7) * 4;
        float a4[4] = {0, 0, 0, 0};
        for (int n = 0; n < 64; ++n) {
            float pv = P2s[n * 36 + k];
            float4 xv = *(const float4*)&X1B[n * 36 + h0];
            a4[0] += pv * xv.x; a4[1] += pv * xv.y; a4[2] += pv * xv.z; a4[3] += pv * xv.w;
        }
        __syncthreads();
        *(float4*)&X2A[k * 36 + h0] = make_float4(a4[0], a4[1], a4[2], a4[3]);
        __syncthreads();
    }
    float* OADJ2s = A + 3456;      // 32x36
    float* Wrel3s = A + 4608;      // 1024
    float* Wroot3s = A + 5632;     // 1024
    float* C1b = A + 6656;         // 32x36
    float* X2B = A + 7808;         // 32x36
    for (int i = tid; i < 1024; i += 256) {
        OADJ2s[(i >> 5) * 36 + (i & 31)] = OADJ2G[(size_t)b * 1024 + i];
        Wrel3s[i] = Wrel3[i];
        Wroot3s[i] = Wroot3[i];
    }
    __syncthreads();
    {
        int n = tid >> 3, j0 = (tid & 7) * 4;
        float a4[4] = {0, 0, 0, 0};
        for (int m = 0; m < 32; ++m) {
            float av = OADJ2s[n * 36 + m];
            float4 xv = *(const float4*)&X2A[m * 36 + j0];
            a4[0] += av * xv.x; a4[1] += av * xv.y; a4[2] += av * xv.z; a4[3] += av * xv.w;
        }
        __syncthreads();
        *(float4*)&C1b[n * 36 + j0] = make_float4(a4[0], a4[1], a4[2], a4[3]);
        __syncthreads();
        float o4[4];
#pragma unroll
        for (int j = 0; j < 4; ++j) o4[j] = brel3[j0 + j];
        for (int h = 0; h < 32; ++h) {
            float c1v = C1b[n * 36 + h];
            float xav = X2A[n * 36 + h];
            float4 wr = *(const float4*)&Wrel3s[h * 32 + j0];
            float4 wo = *(const float4*)&Wroot3s[h * 32 + j0];
            o4[0] += c1v * wr.x + xav * wo.x;
            o4[1] += c1v * wr.y + xav * wo.y;
            o4[2] += c1v * wr.z + xav * wo.z;
            o4[3] += c1v * wr.w + xav * wo.w;
        }
        __syncthreads();
        *(float4*)&X2B[n * 36 + j0] = make_float4(o4[0], o4[1], o4[2], o4[3]);
        __syncthreads();
    }
    float* P3s = A;                // 256
    float* X3A = A + 8960;         // 8x36
    P3s[tid] = P3G[(size_t)b * 256 + tid];
    __syncthreads();
    {
        int k = tid >> 5, h = tid & 31;
        float a = 0.f;
        for (int n = 0; n < 32; ++n) a += P3s[n * 8 + k] * X2B[n * 36 + h];
        __syncthreads();
        X3A[k * 36 + h] = a;
        __syncthreads();
    }
    {
        float* OADJ3s = A + 256;   // 64
        float* C3 = A + 320;       // 8x36
        float* Wrel4s = A + 9248;  // 2048
        float* Wroot4s = A + 11296;// 2048
        if (tid < 64) OADJ3s[tid] = OADJ3G[(size_t)b * 64 + tid];
        for (int i = tid; i < 2048; i += 256) {
            Wrel4s[i] = Wrel4[i];
            Wroot4s[i] = Wroot4[i];
        }
        __syncthreads();
        int n = tid >> 5, h = tid & 31;
        float a = 0.f;
#pragma unroll
        for (int m = 0; m < 8; ++m) a += OADJ3s[n * 8 + m] * X3A[m * 36 + h];
        C3[n * 36 + h] = a;
        __syncthreads();
        int o0 = (tid & 31) * 2;
        float a0 = brel4[o0], a1 = brel4[o0 + 1];
        for (int hh = 0; hh < 32; ++hh) {
            float c3v = C3[n * 36 + hh];
            float x3v = X3A[n * 36 + hh];
            a0 += c3v * Wrel4s[hh * 64 + o0] + x3v * Wroot4s[hh * 64 + o0];
            a1 += c3v * Wrel4s[hh * 64 + o0 + 1] + x3v * Wroot4s[hh * 64 + o0 + 1];
        }
        float* ob = outx + ((size_t)bt * 8 + n) * 64 + o0;
        ob[0] = a0;
        ob[1] = a1;
    }
}

// ---------------- host launch ----------------

extern "C" void kernel_launch(void* const* d_in, const int* in_sizes, int n_in,
                              void* d_out, int out_size, void* d_ws, size_t ws_size,
                              hipStream_t stream) {
    const float* pos    = (const float*)d_in[0];
    const float* ea     = (const float*)d_in[1];
    const int*   esrc   = (const int*)d_in[2];
    const int*   edst   = (const int*)d_in[3];
    const float* W1     = (const float*)d_in[4];
    const float* b1     = (const float*)d_in[5];
    const float* Wp1    = (const float*)d_in[6];
    const float* bp1    = (const float*)d_in[7];
    const float* Wrel2  = (const float*)d_in[8];
    const float* brel2  = (const float*)d_in[9];
    const float* Wroot2 = (const float*)d_in[10];
    const float* Wp2    = (const float*)d_in[11];
    const float* bp2    = (const float*)d_in[12];
    const float* Wrel3  = (const float*)d_in[13];
    const float* brel3  = (const float*)d_in[14];
    const float* Wroot3 = (const float*)d_in[15];
    const float* Wp3    = (const float*)d_in[16];
    const float* bp3    = (const float*)d_in[17];
    const float* Wrel4  = (const float*)d_in[18];
    const float* brel4  = (const float*)d_in[19];
    const float* Wroot4 = (const float*)d_in[20];
    float* out = (float*)d_out;

    char* w = (char*)d_ws;
    float* GBUF1  = (float*)(w + 4194304);              // 8 MB
    float* X1A    = (float*)(w + 12582912);             // 8 MB
    float* Z      = (float*)(w + 20971520);             // 3 MB
    float* P1     = (float*)(w + 25165824);             // 4 MB
    float* DINV   = (float*)(w + 29360128);             // 64 KB
    float* GDEN1  = (float*)(w + 29507584);             // 1 KB
    float* OADJ1  = (float*)(w + 29622272);             // 1 MB
    float* P2G    = (float*)(w + 30670848);             // 512 KB
    float* OADJ2G = (float*)(w + 31195136);             // 256 KB
    float* P3G    = (float*)(w + 31457280);             // 64 KB
    float* OADJ3G = (float*)(w + 31522816);             // 16 KB
    float* MC     = out + 524288;                       // [mincut, ortho]

    // 1. front (dense edge-built GEMM, b128 B-reads, XCD-swizzled): z, dinv, p1
    k_front<<<NB * 8, 512, 0, stream>>>(esrc, edst, ea, pos, W1, b1, Wp1, bp1,
                                        Z, DINV, P1, MC);
    // 2. pool L1 (XCD-swizzled)
    k_pool1f<<<NB * 8, 256, 0, stream>>>(Z, pos, DINV, P1, W1, b1, X1A);
    // 3. fused L1 adjacency-apply + partial GEMM (XCD-swizzled)
    k_adjssg<<<NB * 4, 256, 0, stream>>>(esrc, edst, P1, GBUF1, GDEN1);
    // 4. finish L1 + per-batch planning, fused (512 threads)
    k_tail_a<<<NB, 512, 0, stream>>>(X1A, GBUF1, GDEN1, P1,
                                     Wrel2, brel2, Wroot2, Wp2, bp2,
                                     Wrel3, brel3, Wroot3, Wp3, bp3,
                                     OADJ1, P2G, OADJ2G, P3G, OADJ3G,
                                     out + 524290, MC, MC + 1);
    // 5. per-(b,t) heavy path (XCD-swizzled)
    k_tail_b<<<NB * TC, 256, 0, stream>>>(X1A, OADJ1, P2G, OADJ2G, P3G, OADJ3G,
                                          Wrel2, brel2, Wroot2,
                                          Wrel3, brel3, Wroot3,
                                          Wrel4, brel4, Wroot4, out);
}

// Round 20
// 147.799 us; speedup vs baseline: 1.0324x; 1.0324x over previous
//
#include <hip/hip_runtime.h>
#include <math.h>

#define NB 64
#define TC 16
#define HC 32
#define NNODES 16384
#define NEDGES 131072
#define EPG 2048
#define EPSV 1e-15f

static inline int GRID(int n) { return (n + 255) / 256; }

template<int V> struct Log2 { static constexpr int v = 1 + Log2<V/2>::v; };
template<> struct Log2<1> { static constexpr int v = 0; };

__device__ inline float blk_sum256(float v, float* rbuf) {
    for (int o = 32; o > 0; o >>= 1) v += __shfl_xor(v, o);
    __syncthreads();
    if ((threadIdx.x & 63) == 0) rbuf[threadIdx.x >> 6] = v;
    __syncthreads();
    return rbuf[0] + rbuf[1] + rbuf[2] + rbuf[3];
}

__device__ inline float blk_sum512(float v, float* rbuf) {
    for (int o = 32; o > 0; o >>= 1) v += __shfl_xor(v, o);
    __syncthreads();
    if ((threadIdx.x & 63) == 0) rbuf[threadIdx.x >> 6] = v;
    __syncthreads();
    float s = 0.f;
#pragma unroll
    for (int i = 0; i < 8; ++i) s += rbuf[i];
    return s;
}

// ---------------- front: dense edge-built GEMM, 512 threads, b128 B-reads ----------------
__global__ __launch_bounds__(512) void k_front(
        const int* __restrict__ esrc, const int* __restrict__ edst,
        const float* __restrict__ ea, const float* __restrict__ pos,
        const float* __restrict__ W1, const float* __restrict__ b1,
        const float* __restrict__ Wp1, const float* __restrict__ bp1,
        float* __restrict__ z, float* __restrict__ dinv_g,
        float* __restrict__ p1, float* __restrict__ mc) {
    __shared__ float dinvs[256];
    __shared__ __align__(16) float as_[1152];   // 32x36
    __shared__ __align__(16) float bs[1536];    // 32x48
    __shared__ __align__(16) float zs[1536];    // 32x48
    __shared__ float xm[1024];                  // 32x32
    __shared__ float s1[2048];                  // 32x64
    __shared__ __align__(16) float wp[2048];    // 32x64
    __shared__ float W1s[96];
    __shared__ float b1s[32];
    __shared__ float bp1s[64];

    int bid = blockIdx.x;
    int b = (bid & 7) * 8 + (bid >> 6);
    int dtile = ((bid >> 3) & 7) * 32;
    int tid = threadIdx.x;
    if (bid == 0 && tid < 2) mc[tid] = 0.f;
    ((float4*)wp)[tid] = ((const float4*)Wp1)[tid];     // 512 float4
    if (tid < 96) W1s[tid] = W1[tid];
    if (tid < 32) b1s[tid] = b1[tid];
    if (tid < 64) bp1s[tid] = bp1[tid];

    int ebase = b * EPG;
    int svr[4], dvr[4];
    float evr[4];
#pragma unroll
    for (int j = 0; j < 4; ++j) {
        int e = ebase + tid + j * 512;
        svr[j] = esrc[e] & 255;
        dvr[j] = edst[e] & 255;
        evr[j] = ea[e];
    }
    if (tid < 256) dinvs[tid] = 1.0f;
    __syncthreads();
#pragma unroll
    for (int j = 0; j < 4; ++j) atomicAdd(&dinvs[dvr[j]], evr[j]);
    __syncthreads();
    float dvv = 0.f;
    if (tid < 256) {
        float dg = dinvs[tid];
        dvv = (dg > 0.f) ? rsqrtf(dg) : 0.f;
    }
    __syncthreads();
    if (tid < 256) dinvs[tid] = dvv;
    __syncthreads();
    if (dtile == 0 && tid < 256) dinv_g[b * 256 + tid] = dinvs[tid];

    int d = tid >> 4, q = tid & 15;
    bool act = (q < 12);
    float4 acc = make_float4(0.f, 0.f, 0.f, 0.f);
    const float* pbase = pos + (size_t)b * 256 * 48;
    for (int s0 = 0; s0 < 256; s0 += 32) {
        for (int i = tid; i < 288; i += 512)
            ((float4*)as_)[i] = make_float4(0.f, 0.f, 0.f, 0.f);
        __syncthreads();
#pragma unroll
        for (int j = 0; j < 4; ++j) {
            int dr = dvr[j] - dtile, sc = svr[j] - s0;
            if ((unsigned)dr < 32u && (unsigned)sc < 32u)
                atomicAdd(&as_[dr * 36 + sc], evr[j]);
        }
        for (int i = tid; i < 384; i += 512) {
            int r = i / 12, c = i % 12;
            float4 v = *(const float4*)(pbase + (size_t)(s0 + r) * 48 + c * 4);
            float dd = dinvs[s0 + r];
            v.x *= dd; v.y *= dd; v.z *= dd; v.w *= dd;
            *(float4*)(bs + r * 48 + c * 4) = v;
        }
        __syncthreads();
        if (act) {
#pragma unroll 8
            for (int sp = 0; sp < 32; ++sp) {
                float a = as_[d * 36 + sp];
                float4 bv = *(const float4*)&bs[sp * 48 + q * 4];
                acc.x += a * bv.x;
                acc.y += a * bv.y;
                acc.z += a * bv.z;
                acc.w += a * bv.w;
            }
        }
        __syncthreads();
    }
    if (act) {
        float dd = dinvs[dtile + d];
        float d2 = dd * dd;
        size_t goff = ((size_t)(b * 256 + dtile + d)) * 48 + q * 4;
        float4 pv = *(const float4*)(pos + goff);
        float4 zv;
        zv.x = acc.x * dd; zv.y = acc.y * dd; zv.z = acc.z * dd; zv.w = acc.w * dd;
        *(float4*)(z + goff) = zv;
        float4 av;
        av.x = zv.x + pv.x * d2;
        av.y = zv.y + pv.y * d2;
        av.z = zv.z + pv.z * d2;
        av.w = zv.w + pv.w * d2;
        *(float4*)&zs[d * 48 + q * 4] = av;
    }
    __syncthreads();
    {
        int h = tid & 31, ng = tid >> 5;
        float w0 = W1s[h], w1 = W1s[32 + h], w2 = W1s[64 + h], bb = b1s[h];
#pragma unroll
        for (int j = 0; j < 2; ++j) {
            int nn = ng * 2 + j;
            float a = 0.f;
#pragma unroll
            for (int t = 0; t < 16; ++t) {
                const float* ap = &zs[nn * 48 + t * 3];
                float y = fmaxf(ap[0] * w0 + ap[1] * w1 + ap[2] * w2 + bb, 0.f);
                a += y;
            }
            xm[nn * 32 + h] = a * (1.0f / 16.0f);
        }
    }
    __syncthreads();
    for (int i = tid; i < 2048; i += 512) {
        int n = i >> 6, k = i & 63;
        float a = bp1s[k];
#pragma unroll 8
        for (int h2 = 0; h2 < 32; ++h2) a += xm[n * 32 + h2] * wp[h2 * 64 + k];
        s1[i] = tanhf(a);
    }
    __syncthreads();
    {
        int wid = tid >> 6, lane = tid & 63;
        for (int r0 = wid; r0 < 32; r0 += 8) {
            float v = s1[r0 * 64 + lane];
            float m = v;
            for (int o = 32; o > 0; o >>= 1) m = fmaxf(m, __shfl_xor(m, o));
            float e = expf(v - m);
            float s = e;
            for (int o = 32; o > 0; o >>= 1) s += __shfl_xor(s, o);
            p1[((size_t)b * 256 + dtile + r0) * 64 + lane] = e / s;
        }
    }
}

// ---------------- pool1 fused: recompute y from z, pool in LDS ----------------
__global__ __launch_bounds__(256) void k_pool1f(
        const float* __restrict__ z, const float* __restrict__ pos,
        const float* __restrict__ dinv, const float* __restrict__ p1,
        const float* __restrict__ W1, const float* __restrict__ b1,
        float* __restrict__ X1A) {
    __shared__ __align__(16) float ps[4096];
    __shared__ __align__(16) float ys[4096];
    __shared__ float zc[384];
    __shared__ float pc[384];
    __shared__ float dv[64];
    __shared__ float W1s[96];
    __shared__ float b1s[32];
    int bid = blockIdx.x;
    int b = (bid & 7) * 8 + (bid >> 6);
    int t0 = ((bid >> 3) & 7) * 2;
    int tid = threadIdx.x;
    if (tid < 96) W1s[tid] = W1[tid];
    if (tid < 32) b1s[tid] = b1[tid];
    __syncthreads();
    int hh = tid & 31;
    float w0 = W1s[hh], w1 = W1s[32 + hh], w2 = W1s[64 + hh], bb = b1s[hh];
    int th = tid >> 7, r = tid & 127;
    int k0 = (r >> 3) * 4, h0 = (r & 7) * 4;
    float acc[4][4];
#pragma unroll
    for (int a = 0; a < 4; ++a)
#pragma unroll
        for (int c = 0; c < 4; ++c) acc[a][c] = 0.f;
    for (int n0 = 0; n0 < 256; n0 += 64) {
        for (int i = tid; i < 1024; i += 256)
            ((float4*)ps)[i] = ((const float4*)(p1 + ((size_t)b * 256 + n0) * 64))[i];
        if (tid < 192) {
            int n = tid / 3, c = tid % 3;
            size_t off = ((size_t)(b * 256 + n0 + n)) * 48 + t0 * 3 + c * 2;
            *(float2*)&zc[n * 6 + c * 2] = *(const float2*)(z + off);
            *(float2*)&pc[n * 6 + c * 2] = *(const float2*)(pos + off);
        }
        if (tid < 64) dv[tid] = dinv[b * 256 + n0 + tid];
        __syncthreads();
        int g = tid >> 5;
#pragma unroll
        for (int j = 0; j < 16; ++j) {
            int pidx = g * 16 + j;
            int t = pidx >> 6, nn = pidx & 63;
            float d2 = dv[nn] * dv[nn];
            const float* zp = &zc[nn * 6 + t * 3];
            const float* pp = &pc[nn * 6 + t * 3];
            float a0 = zp[0] + pp[0] * d2;
            float a1 = zp[1] + pp[1] * d2;
            float a2 = zp[2] + pp[2] * d2;
            ys[t * 2048 + nn * 32 + hh] = fmaxf(a0 * w0 + a1 * w1 + a2 * w2 + bb, 0.f);
        }
        __syncthreads();
#pragma unroll 4
        for (int n = 0; n < 64; ++n) {
            float4 kv4 = *(const float4*)&ps[n * 64 + k0];
            float4 xv4 = *(const float4*)&ys[th * 2048 + n * 32 + h0];
            float kv[4] = {kv4.x, kv4.y, kv4.z, kv4.w};
            float xv[4] = {xv4.x, xv4.y, xv4.z, xv4.w};
#pragma unroll
            for (int a = 0; a < 4; ++a)
#pragma unroll
                for (int c = 0; c < 4; ++c) acc[a][c] += kv[a] * xv[c];
        }
        __syncthreads();
    }
    float* ob = X1A + (((size_t)(b * 16 + t0 + th) * 64 + k0) * 32 + h0);
#pragma unroll
    for (int a = 0; a < 4; ++a) {
        float4 v = {acc[a][0], acc[a][1], acc[a][2], acc[a][3]};
        *(float4*)(ob + (size_t)a * 32) = v;
    }
}

// ---------------- L1: adjacency-apply + dflat ----------------
__global__ void k_adjp2(const int* __restrict__ esrc, const int* __restrict__ edst,
                        const float* __restrict__ p, float* __restrict__ tmp,
                        float* __restrict__ dflat) {
    __shared__ __align__(16) float as_[32 * 260];
    __shared__ __align__(16) float ps[64 * 64];
    int bid = blockIdx.x;
    int b = (bid & 7) * 8 + (bid >> 6);
    int nt0 = ((bid >> 3) & 7) * 32;
    int tid = threadIdx.x;
    for (int i = tid; i < 32 * 260 / 4; i += 256)
        ((float4*)as_)[i] = make_float4(0.f, 0.f, 0.f, 0.f);
    __syncthreads();
    int ebase = b * EPG;
#pragma unroll
    for (int j = 0; j < 8; ++j) {
        int e = ebase + tid + j * 256;
        int sv = esrc[e] & 255;
        int nr = sv - nt0;
        if ((unsigned)nr < 32u)
            atomicAdd(&as_[nr * 260 + (edst[e] & 255)], 1.0f);
    }
    __syncthreads();
    int n = tid >> 3, l0 = (tid & 7) * 8;
    float acc[8];
#pragma unroll
    for (int j = 0; j < 8; ++j) acc[j] = 0.f;
    float rs = 0.f;
    for (int m0 = 0; m0 < 256; m0 += 64) {
        for (int i = tid; i < 64 * 64 / 4; i += 256)
            ((float4*)ps)[i] = ((const float4*)(p + ((size_t)b * 256 + m0) * 64))[i];
        __syncthreads();
#pragma unroll 4
        for (int m = 0; m < 64; ++m) {
            float av = as_[n * 260 + m0 + m];
            rs += av;
            float4 p0 = *(const float4*)&ps[m * 64 + l0];
            float4 p1v = *(const float4*)&ps[m * 64 + l0 + 4];
            acc[0] += av * p0.x; acc[1] += av * p0.y; acc[2] += av * p0.z; acc[3] += av * p0.w;
            acc[4] += av * p1v.x; acc[5] += av * p1v.y; acc[6] += av * p1v.z; acc[7] += av * p1v.w;
        }
        __syncthreads();
    }
#pragma unroll
    for (int j = 0; j < 8; ++j)
        tmp[((size_t)b * 256 + nt0 + n) * 64 + l0 + j] = acc[j];
    if ((tid & 7) == 0) dflat[(size_t)b * 256 + nt0 + n] = rs;
}

template<int NC, int KC, int NSPLIT, int KT, int LT>
__global__ void k_ssgp(const float* __restrict__ p, const float* __restrict__ tmp,
                       const float* __restrict__ dflat, float* __restrict__ G,
                       float* __restrict__ Gden) {
    constexpr int NCH = NC / NSPLIT;
    constexpr int LC = 2 * KC;
    constexpr int KQ = KC / 4;
    __shared__ __align__(16) float ab[NCH * LC];
    __shared__ float rbuf[4];
    int bid = blockIdx.x;
    int idx = bid >> 3;
    int b = (bid & 7) * 8 + idx / NSPLIT;
    int split = idx % NSPLIT;
    int n0 = split * NCH;
    int tid = threadIdx.x;
    const float* pb = p + ((size_t)b * NC + n0) * KC;
    const float* tb = tmp + ((size_t)b * NC + n0) * KC;
    const float* db = dflat + (size_t)b * NC + n0;
    for (int i = tid; i < NCH * KQ; i += 256) {
        int r = i / KQ, c = i % KQ;
        *(float4*)(ab + r * LC + c * 4) = ((const float4*)pb)[i];
        *(float4*)(ab + r * LC + KC + c * 4) = ((const float4*)tb)[i];
    }
    __syncthreads();
    float den = 0.f;
    for (int i = tid; i < NCH * KQ; i += 256) {
        int r = i / KQ, c = i % KQ;
        float4 v = *(const float4*)(ab + r * LC + c * 4);
        den += (v.x * v.x + v.y * v.y + v.z * v.z + v.w * v.w) * db[r];
    }
    int kt = tid >> 4, lt = tid & 15;
    int k0 = kt * KT, l0 = lt * LT;
    float acc[KT][LT];
#pragma unroll
    for (int r = 0; r < KT; ++r)
#pragma unroll
        for (int c = 0; c < LT; ++c) acc[r][c] = 0.f;
#pragma unroll 4
    for (int n = 0; n < NCH; ++n) {
        float kv[KT], lv[LT];
#pragma unroll
        for (int r = 0; r < KT; ++r) kv[r] = ab[n * LC + k0 + r];
#pragma unroll
        for (int c = 0; c < LT; ++c) lv[c] = ab[n * LC + l0 + c];
#pragma unroll
        for (int r = 0; r < KT; ++r)
#pragma unroll
            for (int c = 0; c < LT; ++c) acc[r][c] += kv[r] * lv[c];
    }
    float* Gb = G + ((size_t)split * NB + b) * (KC * LC);
#pragma unroll
    for (int r = 0; r < KT; ++r)
#pragma unroll
        for (int c = 0; c < LT; ++c)
            Gb[(k0 + r) * LC + l0 + c] = acc[r][c];
    float dt = blk_sum256(den, rbuf);
    if (tid == 0) Gden[(size_t)split * NB + b] = dt;
}

// ---------------- tail A: finish L1 + per-batch planning, 512 threads ----------------
__global__ __launch_bounds__(512) void k_tail_a(
        const float* __restrict__ X1A, const float* __restrict__ GBUF1,
        const float* __restrict__ GDEN1, const float* __restrict__ p1,
        const float* __restrict__ Wrel2, const float* __restrict__ brel2,
        const float* __restrict__ Wroot2,
        const float* __restrict__ Wp2, const float* __restrict__ bp2,
        const float* __restrict__ Wrel3, const float* __restrict__ brel3,
        const float* __restrict__ Wroot3,
        const float* __restrict__ Wp3, const float* __restrict__ bp3,
        float* __restrict__ OADJ1G, float* __restrict__ P2G,
        float* __restrict__ OADJ2G, float* __restrict__ P3G,
        float* __restrict__ OADJ3G, float* __restrict__ outagg,
        float* __restrict__ mc_out, float* __restrict__ or_out) {
    __shared__ __align__(16) float lds[16160];
    float* P2     = lds;            // 64x36
    float* XM2    = lds + 2304;     // 64x36
    float* OADJ2L = lds + 4608;     // 32x36
    float* P3L    = lds + 5760;     // 32x8
    float* OADJ3L = lds + 6016;     // 8x8
    float* DF3    = lds + 6080;     // 32
    float* DVV    = lds + 6112;     // 40
    float* RBUF   = lds + 6152;     // 8
    float* OADJ1s = lds + 6160;     // 64x68
    float* S      = lds + 10512;    // scratch (max use 5504)
    float* DF2    = lds + 16080;    // 64 (persist)

    int bid = blockIdx.x;
    int b = ((bid & 7) << 3) | (bid >> 3);
    int tid = threadIdx.x;

    // ---- Phase F: finish L1
    {
        float* FS = lds;           // 64x65
        float* FO = lds + 4160;
        float* FD = lds + 8320;
        float* FR = lds + 8384;
#pragma unroll
        for (int j = 0; j < 8; ++j) {
            int i = tid + j * 512;
            int k = i >> 6, l = i & 63;
            float sv = 0.f, ov = 0.f;
#pragma unroll
            for (int s = 0; s < 4; ++s) {
                const float* Gb = GBUF1 + ((size_t)s * NB + b) * 8192;
                sv += Gb[k * 128 + l];
                ov += Gb[k * 128 + 64 + l];
            }
            FS[k * 65 + l] = sv;
            FO[k * 65 + l] = ov;
        }
        __syncthreads();
        float ssn2 = 0.f;
#pragma unroll
        for (int j = 0; j < 8; ++j) {
            int i = tid + j * 512;
            float v = FS[(i >> 6) * 65 + (i & 63)];
            ssn2 += v * v;
        }
        float num = 0.f;
        if (tid < 64) num = FO[tid * 65 + tid];
        float den_t = 0.f;
#pragma unroll
        for (int s = 0; s < 4; ++s) den_t += GDEN1[(size_t)s * NB + b];
        float ssn2_t = blk_sum512(ssn2, FR);
        float num_t = blk_sum512(num, FR);
        float inv = 1.0f / sqrtf(ssn2_t);
        float dk = rsqrtf(64.0f);
        float o2 = 0.f;
#pragma unroll
        for (int j = 0; j < 8; ++j) {
            int i = tid + j * 512;
            int k = i >> 6, l = i & 63;
            float v = FS[k * 65 + l] * inv - ((k == l) ? dk : 0.f);
            o2 += v * v;
        }
        float o2_t = blk_sum512(o2, FR);
        if (tid == 0) {
            atomicAdd(mc_out, -(num_t / den_t) * (1.0f / NB));
            atomicAdd(or_out, sqrtf(o2_t) * (1.0f / NB));
        }
        if (tid < 64) {
            float rs = 0.f;
            for (int l = 0; l < 64; ++l) rs += FO[tid * 65 + l];
            rs -= FO[tid * 65 + tid];
            FD[tid] = sqrtf(rs) + EPSV;
        }
        __syncthreads();
        float ov8[8];
#pragma unroll
        for (int j = 0; j < 8; ++j) {
            int i = tid + j * 512;
            int k = i >> 6, l = i & 63;
            ov8[j] = (k == l) ? 0.f : FO[k * 65 + l] / (FD[k] * FD[l]);
        }
        __syncthreads();
#pragma unroll
        for (int j = 0; j < 8; ++j) {
            int i = tid + j * 512;
            int k = i >> 6, l = i & 63;
            OADJ1s[k * 68 + l] = ov8[j];
            OADJ1G[(size_t)b * 4096 + i] = ov8[j];
        }
        __syncthreads();
        if (tid < 64) {
            float rs = 0.f;
            for (int l = 0; l < 64; ++l) rs += OADJ1s[tid * 68 + l];
            DF2[tid] = rs;
        }
        __syncthreads();
    }

    // ---- Phase 0: XM1A = mean_t X1A; XM2 = graphconv2(XM1A)
    float* XM1A = S;
    for (int i = tid; i < 2048; i += 512) {
        float s = 0.f;
        for (int t = 0; t < 16; ++t) s += X1A[((size_t)b * 16 + t) * 2048 + i];
        XM1A[(i >> 5) * 36 + (i & 31)] = s * (1.0f / 16.0f);
    }
    {
        float* WR = P2;
        float* WO = P2 + 1024;
        for (int i = tid; i < 1024; i += 512) { WR[i] = Wrel2[i]; WO[i] = Wroot2[i]; }
        __syncthreads();
        float* C1 = S + 2304;
        int n = tid >> 3, j0 = (tid & 7) * 4;
        float a4[4] = {0, 0, 0, 0};
        for (int m = 0; m < 64; ++m) {
            float av = OADJ1s[n * 68 + m];
            float4 xv = *(const float4*)&XM1A[m * 36 + j0];
            a4[0] += av * xv.x; a4[1] += av * xv.y; a4[2] += av * xv.z; a4[3] += av * xv.w;
        }
        __syncthreads();
#pragma unroll
        for (int j = 0; j < 4; ++j) C1[n * 36 + j0 + j] = a4[j];
        __syncthreads();
        float o4[4];
#pragma unroll
        for (int j = 0; j < 4; ++j) o4[j] = brel2[j0 + j];
        for (int h = 0; h < 32; ++h) {
            float c1v = C1[n * 36 + h];
            float xav = XM1A[n * 36 + h];
            float4 wr = *(const float4*)&WR[h * 32 + j0];
            float4 wo = *(const float4*)&WO[h * 32 + j0];
            o4[0] += c1v * wr.x + xav * wo.x;
            o4[1] += c1v * wr.y + xav * wo.y;
            o4[2] += c1v * wr.z + xav * wo.z;
            o4[3] += c1v * wr.w + xav * wo.w;
        }
        __syncthreads();
#pragma unroll
        for (int j = 0; j < 4; ++j) XM2[n * 36 + j0 + j] = o4[j];
        __syncthreads();
    }
    // ---- Phase 2: P2 = softmax(tanh(XM2@Wp2+bp2))
    {
        float* S2 = S;
        float* WP2s = S + 2048;
        for (int i = tid; i < 1024; i += 512) WP2s[i] = Wp2[i];
        __syncthreads();
        for (int i = tid; i < 2048; i += 512) {
            int n = i >> 5, k = i & 31;
            float a = bp2[k];
            for (int h = 0; h < 32; ++h) a += XM2[n * 36 + h] * WP2s[h * 32 + k];
            S2[i] = tanhf(a);
        }
        __syncthreads();
        int lane = tid & 31, rr = tid >> 5;
        for (int r0 = 0; r0 < 64; r0 += 16) {
            int row = r0 + rr;
            float v = S2[row * 32 + lane];
            float m = v;
            for (int o = 16; o > 0; o >>= 1) m = fmaxf(m, __shfl_xor(m, o, 32));
            float e = expf(v - m);
            float s = e;
            for (int o = 16; o > 0; o >>= 1) s += __shfl_xor(s, o, 32);
            P2[row * 36 + lane] = e / s;
        }
        __syncthreads();
        for (int i = tid; i < 2048; i += 512)
            P2G[(size_t)b * 2048 + i] = P2[(i >> 5) * 36 + (i & 31)];
    }
    // ---- Phase 3: TMP2 = OADJ1 @ P2
    float* TMP2 = S;
    {
        int n = tid >> 3, l0 = (tid & 7) * 4;
        float a4[4] = {0, 0, 0, 0};
        for (int m = 0; m < 64; ++m) {
            float av = OADJ1s[n * 68 + m];
            float4 pv = *(const float4*)&P2[m * 36 + l0];
            a4[0] += av * pv.x; a4[1] += av * pv.y; a4[2] += av * pv.z; a4[3] += av * pv.w;
        }
        __syncthreads();
#pragma unroll
        for (int j = 0; j < 4; ++j) TMP2[n * 36 + l0 + j] = a4[j];
        __syncthreads();
    }
    // ---- Phase 4: GS/GO, losses L2, OADJ2L, DF3
    {
        float* GS = S + 2304;
        float* GO = S + 3360;
        int k = tid >> 4, l0 = (tid & 15) * 2;
        float as2[2] = {0, 0}, ao2[2] = {0, 0};
        for (int n = 0; n < 64; ++n) {
            float pv = P2[n * 36 + k];
            float2 lp = *(const float2*)&P2[n * 36 + l0];
            float2 lt = *(const float2*)&TMP2[n * 36 + l0];
            as2[0] += pv * lp.x; as2[1] += pv * lp.y;
            ao2[0] += pv * lt.x; ao2[1] += pv * lt.y;
        }
        GS[k * 33 + l0] = as2[0]; GS[k * 33 + l0 + 1] = as2[1];
        GO[k * 33 + l0] = ao2[0]; GO[k * 33 + l0 + 1] = ao2[1];
        __syncthreads();
        float den = 0.f;
        for (int i = tid; i < 2048; i += 512) {
            float pv = P2[(i >> 5) * 36 + (i & 31)];
            den += pv * pv * DF2[i >> 5];
        }
        float ssn2 = 0.f;
        for (int i = tid; i < 1024; i += 512) {
            float v = GS[(i >> 5) * 33 + (i & 31)];
            ssn2 += v * v;
        }
        float num = 0.f;
        if (tid < 32) num = GO[tid * 33 + tid];
        float den_t = blk_sum512(den, RBUF);
        float ssn2_t = blk_sum512(ssn2, RBUF);
        float num_t = blk_sum512(num, RBUF);
        float inv = 1.0f / sqrtf(ssn2_t);
        float dk = rsqrtf(32.0f);
        float o2 = 0.f;
        for (int i = tid; i < 1024; i += 512) {
            int kk = i >> 5, ll = i & 31;
            float v = GS[kk * 33 + ll] * inv - ((kk == ll) ? dk : 0.f);
            o2 += v * v;
        }
        float o2_t = blk_sum512(o2, RBUF);
        if (tid == 0) {
            atomicAdd(mc_out, -(num_t / den_t) * (1.0f / NB));
            atomicAdd(or_out, sqrtf(o2_t) * (1.0f / NB));
        }
        if (tid < 32) {
            float rs = 0.f;
            for (int l = 0; l < 32; ++l) rs += GO[tid * 33 + l];
            rs -= GO[tid * 33 + tid];
            DVV[tid] = sqrtf(rs) + EPSV;
        }
        __syncthreads();
        for (int i = tid; i < 1024; i += 512) {
            int kk = i >> 5, ll = i & 31;
            float v = (kk == ll) ? 0.f : GO[kk * 33 + ll] / (DVV[kk] * DVV[ll]);
            OADJ2L[kk * 36 + ll] = v;
            OADJ2G[(size_t)b * 1024 + i] = v;
        }
        __syncthreads();
        if (tid < 32) {
            float s = 0.f;
            for (int l = 0; l < 32; ++l) s += OADJ2L[tid * 36 + l];
            DF3[tid] = s;
        }
        __syncthreads();
    }
    // ---- Phase 5: XM2A = P2^T @ XM2
    float* XM2A = S;
    {
        int k = tid >> 4, h0 = (tid & 15) * 2;
        float a2[2] = {0, 0};
        for (int n = 0; n < 64; ++n) {
            float pv = P2[n * 36 + k];
            float2 xv = *(const float2*)&XM2[n * 36 + h0];
            a2[0] += pv * xv.x; a2[1] += pv * xv.y;
        }
        __syncthreads();
        XM2A[k * 36 + h0] = a2[0];
        XM2A[k * 36 + h0 + 1] = a2[1];
        __syncthreads();
    }
    // ---- Phase 6: XM2B = graphconv3(XM2A)
    float* XM2B = S + 4352;
    {
        float* WREL3s = S + 1152;
        float* WROOT3s = S + 2176;
        float* C1 = S + 3200;
        for (int i = tid; i < 1024; i += 512) {
            WREL3s[i] = Wrel3[i];
            WROOT3s[i] = Wroot3[i];
        }
        __syncthreads();
        int n = tid >> 4, j0 = (tid & 15) * 2;
        float a2[2] = {0, 0};
        for (int m = 0; m < 32; ++m) {
            float av = OADJ2L[n * 36 + m];
            float2 xv = *(const float2*)&XM2A[m * 36 + j0];
            a2[0] += av * xv.x; a2[1] += av * xv.y;
        }
        __syncthreads();
        C1[n * 36 + j0] = a2[0];
        C1[n * 36 + j0 + 1] = a2[1];
        __syncthreads();
        float o2v[2];
        o2v[0] = brel3[j0]; o2v[1] = brel3[j0 + 1];
        for (int h = 0; h < 32; ++h) {
            float c1v = C1[n * 36 + h];
            float xav = XM2A[n * 36 + h];
            float2 wr = *(const float2*)&WREL3s[h * 32 + j0];
            float2 wo = *(const float2*)&WROOT3s[h * 32 + j0];
            o2v[0] += c1v * wr.x + xav * wo.x;
            o2v[1] += c1v * wr.y + xav * wo.y;
        }
        __syncthreads();
        XM2B[n * 36 + j0] = o2v[0];
        XM2B[n * 36 + j0 + 1] = o2v[1];
        __syncthreads();
    }
    // ---- Phase 7: P3 = softmax(tanh(XM2B@Wp3+bp3))
    {
        float* WP3s = S;
        for (int i = tid; i < 256; i += 512) WP3s[i] = Wp3[i];
        __syncthreads();
        if (tid < 256) {
            int n = tid >> 3, kk = tid & 7;
            float a = bp3[kk];
            for (int h = 0; h < 32; ++h) a += XM2B[n * 36 + h] * WP3s[h * 8 + kk];
            float v = tanhf(a);
            float m = v;
            for (int o = 4; o > 0; o >>= 1) m = fmaxf(m, __shfl_xor(m, o, 8));
            float e = expf(v - m);
            float s = e;
            for (int o = 4; o > 0; o >>= 1) s += __shfl_xor(s, o, 8);
            P3L[n * 8 + kk] = e / s;
        }
        __syncthreads();
        if (tid < 256) P3G[(size_t)b * 256 + tid] = P3L[tid];
        __syncthreads();
    }
    // ---- Phase 8: L3 losses + OADJ3
    {
        float* TMP3 = S;
        float* GS3 = S + 256;
        float* GO3 = S + 336;
        if (tid < 256) {
            int n = tid >> 3, l = tid & 7;
            float a = 0.f;
            for (int m = 0; m < 32; ++m) a += OADJ2L[n * 36 + m] * P3L[m * 8 + l];
            TMP3[n * 8 + l] = a;
        }
        __syncthreads();
        if (tid < 64) {
            int k = tid >> 3, ll = tid & 7;
            float accs = 0.f, acco = 0.f;
            for (int nn = 0; nn < 32; ++nn) {
                float pv = P3L[nn * 8 + k];
                accs += pv * P3L[nn * 8 + ll];
                acco += pv * TMP3[nn * 8 + ll];
            }
            GS3[k * 9 + ll] = accs;
            GO3[k * 9 + ll] = acco;
        }
        __syncthreads();
        float den = 0.f;
        if (tid < 256) {
            float pv = P3L[tid];
            den = pv * pv * DF3[tid >> 3];
        }
        float ssn2 = 0.f;
        if (tid < 64) {
            float v = GS3[(tid >> 3) * 9 + (tid & 7)];
            ssn2 = v * v;
        }
        float num = 0.f;
        if (tid < 8) num = GO3[tid * 9 + tid];
        float den_t = blk_sum512(den, RBUF);
        float ssn2_t = blk_sum512(ssn2, RBUF);
        float num_t = blk_sum512(num, RBUF);
        float inv = 1.0f / sqrtf(ssn2_t);
        float dk = rsqrtf(8.0f);
        float o2 = 0.f;
        if (tid < 64) {
            int k = tid >> 3, ll = tid & 7;
            float v = GS3[k * 9 + ll] * inv - ((k == ll) ? dk : 0.f);
            o2 = v * v;
        }
        float o2_t = blk_sum512(o2, RBUF);
        if (tid == 0) {
            atomicAdd(mc_out, -(num_t / den_t) * (1.0f / NB));
            atomicAdd(or_out, sqrtf(o2_t) * (1.0f / NB));
        }
        if (tid < 8) {
            float rs = 0.f;
            for (int ll = 0; ll < 8; ++ll) rs += GO3[tid * 9 + ll];
            rs -= GO3[tid * 9 + tid];
            DVV[32 + tid] = sqrtf(rs) + EPSV;
        }
        __syncthreads();
        if (tid < 64) {
            int k = tid >> 3, ll = tid & 7;
            float v = (k == ll) ? 0.f : GO3[k * 9 + ll] / (DVV[32 + k] * DVV[32 + ll]);
            OADJ3L[tid] = v;
            OADJ3G[(size_t)b * 64 + tid] = v;
        }
        __syncthreads();
    }
    // ---- Phase 9: agg = p1 @ (P2 @ P3)
    {
        float* Q = S;
        {
            int k = tid >> 3, m = tid & 7;
            float a = 0.f;
            for (int l = 0; l < 32; ++l) a += P2[k * 36 + l] * P3L[l * 8 + m];
            Q[tid] = a;
        }
        __syncthreads();
        int row = tid >> 1, m0 = (tid & 1) * 4;
        const float* p1r = p1 + ((size_t)b * 256 + row) * 64;
        float a4[4] = {0, 0, 0, 0};
        for (int k = 0; k < 64; ++k) {
            float pv = p1r[k];
#pragma unroll
            for (int m = 0; m < 4; ++m) a4[m] += pv * Q[k * 8 + m0 + m];
        }
#pragma unroll
        for (int m = 0; m < 4; ++m)
            outagg[((size_t)b * 256 + row) * 8 + m0 + m] = a4[m];
    }
}

// ---------------- tail B: per-(b,t) heavy path, gc2 fused, fully LDS-resident ----------------
__global__ __launch_bounds__(256) void k_tail_b(
        const float* __restrict__ X1A, const float* __restrict__ oadj1,
        const float* __restrict__ P2G, const float* __restrict__ OADJ2G,
        const float* __restrict__ P3G, const float* __restrict__ OADJ3G,
        const float* __restrict__ Wrel2, const float* __restrict__ brel2,
        const float* __restrict__ Wroot2,
        const float* __restrict__ Wrel3, const float* __restrict__ brel3,
        const float* __restrict__ Wroot3,
        const float* __restrict__ Wrel4, const float* __restrict__ brel4,
        const float* __restrict__ Wroot4,
        float* __restrict__ outx) {
    __shared__ float A[13408];
    float* X1AT = A;               // 64x36
    float* OADJ1s = A + 2304;      // 64x68
    float* WrelS = A + 6656;       // 1024
    float* WrootS = A + 7680;      // 1024
    float* C1a = A + 8704;         // 64x36
    float* X1B = A + 11008;        // 64x36
    int bid = blockIdx.x;
    int idxg = bid >> 3;
    int t = idxg & 15;
    int b = (bid & 7) * 8 + (idxg >> 4);
    int bt = b * 16 + t;
    int tid = threadIdx.x;
    for (int i = tid; i < 2048; i += 256)
        X1AT[(i >> 5) * 36 + (i & 31)] = X1A[(size_t)bt * 2048 + i];
    for (int i = tid; i < 4096; i += 256)
        OADJ1s[(i >> 6) * 68 + (i & 63)] = oadj1[(size_t)b * 4096 + i];
    for (int i = tid; i < 1024; i += 256) {
        WrelS[i] = Wrel2[i];
        WrootS[i] = Wroot2[i];
    }
    __syncthreads();
    {
        int n = tid >> 2, j0 = (tid & 3) * 8;
        float a8[8];
#pragma unroll
        for (int j = 0; j < 8; ++j) a8[j] = 0.f;
        for (int m = 0; m < 64; ++m) {
            float av = OADJ1s[n * 68 + m];
            float4 x1 = *(const float4*)&X1AT[m * 36 + j0];
            float4 x2 = *(const float4*)&X1AT[m * 36 + j0 + 4];
            a8[0] += av * x1.x; a8[1] += av * x1.y; a8[2] += av * x1.z; a8[3] += av * x1.w;
            a8[4] += av * x2.x; a8[5] += av * x2.y; a8[6] += av * x2.z; a8[7] += av * x2.w;
        }
        __syncthreads();
#pragma unroll
        for (int j = 0; j < 8; ++j) C1a[n * 36 + j0 + j] = a8[j];
        __syncthreads();
        float o8[8];
#pragma unroll
        for (int j = 0; j < 8; ++j) o8[j] = brel2[j0 + j];
        for (int h = 0; h < 32; ++h) {
            float c1v = C1a[n * 36 + h];
            float xav = X1AT[n * 36 + h];
            float4 wr1 = *(const float4*)&WrelS[h * 32 + j0];
            float4 wr2 = *(const float4*)&WrelS[h * 32 + j0 + 4];
            float4 wo1 = *(const float4*)&WrootS[h * 32 + j0];
            float4 wo2 = *(const float4*)&WrootS[h * 32 + j0 + 4];
            o8[0] += c1v * wr1.x + xav * wo1.x; o8[1] += c1v * wr1.y + xav * wo1.y;
            o8[2] += c1v * wr1.z + xav * wo1.z; o8[3] += c1v * wr1.w + xav * wo1.w;
            o8[4] += c1v * wr2.x + xav * wo2.x; o8[5] += c1v * wr2.y + xav * wo2.y;
            o8[6] += c1v * wr2.z + xav * wo2.z; o8[7] += c1v * wr2.w + xav * wo2.w;
        }
        __syncthreads();
#pragma unroll
        for (int j = 0; j < 8; ++j) X1B[n * 36 + j0 + j] = o8[j];
        __syncthreads();
    }
    float* P2s = A;                // 64x36
    float* X2A = A + 2304;         // 32x36
    for (int i = tid; i < 2048; i += 256)
        P2s[(i >> 5) * 36 + (i & 31)] = P2G[(size_t)b * 2048 + i];
    __syncthreads();
    {
        int k = tid >> 3, h0 = (tid & 7) * 4;
        float a4[4] = {0, 0, 0, 0};
        for (int n = 0; n < 64; ++n) {
            float pv = P2s[n * 36 + k];
            float4 xv = *(const float4*)&X1B[n * 36 + h0];
            a4[0] += pv * xv.x; a4[1] += pv * xv.y; a4[2] += pv * xv.z; a4[3] += pv * xv.w;
        }
        __syncthreads();
        *(float4*)&X2A[k * 36 + h0] = make_float4(a4[0], a4[1], a4[2], a4[3]);
        __syncthreads();
    }
    float* OADJ2s = A + 3456;      // 32x36
    float* Wrel3s = A + 4608;      // 1024
    float* Wroot3s = A + 5632;     // 1024
    float* C1b = A + 6656;         // 32x36
    float* X2B = A + 7808;         // 32x36
    for (int i = tid; i < 1024; i += 256) {
        OADJ2s[(i >> 5) * 36 + (i & 31)] = OADJ2G[(size_t)b * 1024 + i];
        Wrel3s[i] = Wrel3[i];
        Wroot3s[i] = Wroot3[i];
    }
    __syncthreads();
    {
        int n = tid >> 3, j0 = (tid & 7) * 4;
        float a4[4] = {0, 0, 0, 0};
        for (int m = 0; m < 32; ++m) {
            float av = OADJ2s[n * 36 + m];
            float4 xv = *(const float4*)&X2A[m * 36 + j0];
            a4[0] += av * xv.x; a4[1] += av * xv.y; a4[2] += av * xv.z; a4[3] += av * xv.w;
        }
        __syncthreads();
        *(float4*)&C1b[n * 36 + j0] = make_float4(a4[0], a4[1], a4[2], a4[3]);
        __syncthreads();
        float o4[4];
#pragma unroll
        for (int j = 0; j < 4; ++j) o4[j] = brel3[j0 + j];
        for (int h = 0; h < 32; ++h) {
            float c1v = C1b[n * 36 + h];
            float xav = X2A[n * 36 + h];
            float4 wr = *(const float4*)&Wrel3s[h * 32 + j0];
            float4 wo = *(const float4*)&Wroot3s[h * 32 + j0];
            o4[0] += c1v * wr.x + xav * wo.x;
            o4[1] += c1v * wr.y + xav * wo.y;
            o4[2] += c1v * wr.z + xav * wo.z;
            o4[3] += c1v * wr.w + xav * wo.w;
        }
        __syncthreads();
        *(float4*)&X2B[n * 36 + j0] = make_float4(o4[0], o4[1], o4[2], o4[3]);
        __syncthreads();
    }
    float* P3s = A;                // 256
    float* X3A = A + 8960;         // 8x36
    P3s[tid] = P3G[(size_t)b * 256 + tid];
    __syncthreads();
    {
        int k = tid >> 5, h = tid & 31;
        float a = 0.f;
        for (int n = 0; n < 32; ++n) a += P3s[n * 8 + k] * X2B[n * 36 + h];
        __syncthreads();
        X3A[k * 36 + h] = a;
        __syncthreads();
    }
    {
        float* OADJ3s = A + 256;   // 64
        float* C3 = A + 320;       // 8x36
        float* Wrel4s = A + 9248;  // 2048
        float* Wroot4s = A + 11296;// 2048
        if (tid < 64) OADJ3s[tid] = OADJ3G[(size_t)b * 64 + tid];
        for (int i = tid; i < 2048; i += 256) {
            Wrel4s[i] = Wrel4[i];
            Wroot4s[i] = Wroot4[i];
        }
        __syncthreads();
        int n = tid >> 5, h = tid & 31;
        float a = 0.f;
#pragma unroll
        for (int m = 0; m < 8; ++m) a += OADJ3s[n * 8 + m] * X3A[m * 36 + h];
        C3[n * 36 + h] = a;
        __syncthreads();
        int o0 = (tid & 31) * 2;
        float a0 = brel4[o0], a1 = brel4[o0 + 1];
        for (int hh = 0; hh < 32; ++hh) {
            float c3v = C3[n * 36 + hh];
            float x3v = X3A[n * 36 + hh];
            a0 += c3v * Wrel4s[hh * 64 + o0] + x3v * Wroot4s[hh * 64 + o0];
            a1 += c3v * Wrel4s[hh * 64 + o0 + 1] + x3v * Wroot4s[hh * 64 + o0 + 1];
        }
        float* ob = outx + ((size_t)bt * 8 + n) * 64 + o0;
        ob[0] = a0;
        ob[1] = a1;
    }
}

// ---------------- host launch ----------------

extern "C" void kernel_launch(void* const* d_in, const int* in_sizes, int n_in,
                              void* d_out, int out_size, void* d_ws, size_t ws_size,
                              hipStream_t stream) {
    const float* pos    = (const float*)d_in[0];
    const float* ea     = (const float*)d_in[1];
    const int*   esrc   = (const int*)d_in[2];
    const int*   edst   = (const int*)d_in[3];
    const float* W1     = (const float*)d_in[4];
    const float* b1     = (const float*)d_in[5];
    const float* Wp1    = (const float*)d_in[6];
    const float* bp1    = (const float*)d_in[7];
    const float* Wrel2  = (const float*)d_in[8];
    const float* brel2  = (const float*)d_in[9];
    const float* Wroot2 = (const float*)d_in[10];
    const float* Wp2    = (const float*)d_in[11];
    const float* bp2    = (const float*)d_in[12];
    const float* Wrel3  = (const float*)d_in[13];
    const float* brel3  = (const float*)d_in[14];
    const float* Wroot3 = (const float*)d_in[15];
    const float* Wp3    = (const float*)d_in[16];
    const float* bp3    = (const float*)d_in[17];
    const float* Wrel4  = (const float*)d_in[18];
    const float* brel4  = (const float*)d_in[19];
    const float* Wroot4 = (const float*)d_in[20];
    float* out = (float*)d_out;

    char* w = (char*)d_ws;
    float* TMP    = (float*)(w);                        // 4 MB
    float* GBUF1  = (float*)(w + 4194304);              // 8 MB
    float* X1A    = (float*)(w + 12582912);             // 8 MB
    float* Z      = (float*)(w + 20971520);             // 3 MB
    float* P1     = (float*)(w + 25165824);             // 4 MB
    float* DINV   = (float*)(w + 29360128);             // 64 KB
    float* DFLAT  = (float*)(w + 29425664);             // 64 KB
    float* GDEN1  = (float*)(w + 29507584);             // 1 KB
    float* OADJ1  = (float*)(w + 29622272);             // 1 MB
    float* P2G    = (float*)(w + 30670848);             // 512 KB
    float* OADJ2G = (float*)(w + 31195136);             // 256 KB
    float* P3G    = (float*)(w + 31457280);             // 64 KB
    float* OADJ3G = (float*)(w + 31522816);             // 16 KB
    float* MC     = out + 524288;                       // [mincut, ortho]

    // 1. front (dense edge-built GEMM, b128 B-reads, XCD-swizzled): z, dinv, p1
    k_front<<<NB * 8, 512, 0, stream>>>(esrc, edst, ea, pos, W1, b1, Wp1, bp1,
                                        Z, DINV, P1, MC);
    // 2. pool L1 (XCD-swizzled)
    k_pool1f<<<NB * 8, 256, 0, stream>>>(Z, pos, DINV, P1, W1, b1, X1A);
    // 3-4. L1 mincut chain (XCD-swizzled)
    k_adjp2<<<NB * 8, 256, 0, stream>>>(esrc, edst, P1, TMP, DFLAT);
    k_ssgp<256, 64, 4, 4, 8><<<NB * 4, 256, 0, stream>>>(P1, TMP, DFLAT, GBUF1, GDEN1);
    // 5. finish L1 + per-batch planning, fused (512 threads)
    k_tail_a<<<NB, 512, 0, stream>>>(X1A, GBUF1, GDEN1, P1,
                                     Wrel2, brel2, Wroot2, Wp2, bp2,
                                     Wrel3, brel3, Wroot3, Wp3, bp3,
                                     OADJ1, P2G, OADJ2G, P3G, OADJ3G,
                                     out + 524290, MC, MC + 1);
    // 6. per-(b,t) heavy path (XCD-swizzled)
    k_tail_b<<<NB * TC, 256, 0, stream>>>(X1A, OADJ1, P2G, OADJ2G, P3G, OADJ3G,
                                          Wrel2, brel2, Wroot2,
                                          Wrel3, brel3, Wroot3,
                                          Wrel4, brel4, Wroot4, out);
}